// Round 7
// baseline (101.300 us; speedup 1.0000x reference)
//
#include <hip/hip_runtime.h>
#include <hip/hip_bf16.h>
#include <math.h>

#define B_   64
#define C_   768
#define C2_  1536
#define R_   96
#define E_   16
#define HW_  1024
#define GRID_ 256
#define THR_  512

typedef float f32x4 __attribute__((ext_vector_type(4)));

__device__ __forceinline__ float gelu_exact(float x) {
    return 0.5f * x * (1.0f + erff(x * 0.70710678118654752440f));
}

// relaxed agent-scope store: reaches coherence point, no L2 wb/inv emitted.
__device__ __forceinline__ void st_sc1(float* p, float v) {
    __hip_atomic_store(p, v, __ATOMIC_RELAXED, __HIP_MEMORY_SCOPE_AGENT);
}

// Grid barrier: RMW arrival (after vmcnt(0) drain), LOAD-only poll.
// Relaxed agent atomic load = L2-bypassing read, no RMW serialization,
// no acquire cache maintenance.
__device__ __forceinline__ void arrive_wait(unsigned* ctr, unsigned target) {
    __syncthreads();
    if (threadIdx.x == 0) {
        asm volatile("s_waitcnt vmcnt(0)" ::: "memory");
        __hip_atomic_fetch_add(ctr, 1u, __ATOMIC_RELAXED, __HIP_MEMORY_SCOPE_AGENT);
        int it = 0;
        while (__hip_atomic_load(ctr, __ATOMIC_RELAXED,
                                 __HIP_MEMORY_SCOPE_AGENT) < target) {
            __builtin_amdgcn_s_sleep(8);
            if (++it > (1 << 22)) break;   // safety valve: fail, don't hang
        }
    }
    __syncthreads();
}

// -------- ONE kernel: pool + entire gating chain, grid-synced ---------------
__global__ __launch_bounds__(512) void fused_all(
    const float* __restrict__ x,
    const float* __restrict__ w1, const float* __restrict__ b1,
    const float* __restrict__ bn1_g, const float* __restrict__ bn1_b,
    const float* __restrict__ bn1_m, const float* __restrict__ bn1_v,
    const float* __restrict__ caw1, const float* __restrict__ cab1,
    const float* __restrict__ caw2, const float* __restrict__ cab2,
    const float* __restrict__ w2, const float* __restrict__ b2,
    const float* __restrict__ bn2_g, const float* __restrict__ bn2_b,
    const float* __restrict__ bn2_m, const float* __restrict__ bn2_v,
    const float* __restrict__ w3, const float* __restrict__ b3,
    float* __restrict__ gT, float* __restrict__ h1T, float* __restrict__ rT,
    float* __restrict__ h1gT, float* __restrict__ h2T,
    float* __restrict__ out, unsigned* __restrict__ ctr)
{
    __shared__ float smem[13456];   // 53.8 KB, reused per phase
    const int t   = threadIdx.x;
    const int bid = blockIdx.x;
    const int b   = t & 63;
    const int w   = t >> 6;

    // ---- P0: global average pool [B,C,H,W] -> gT[C][B]; 24 rows per wave ---
    {
        const int wid = bid * 8 + w;          // 0..2047
        #pragma unroll 2
        for (int i = 0; i < 24; ++i) {
            const int row = wid * 24 + i;     // 0..49151
            const int pb = row / C_;
            const int pc = row - pb * C_;
            const f32x4* p = reinterpret_cast<const f32x4*>(x + (size_t)row * HW_);
            f32x4 a0 = __builtin_nontemporal_load(p + b +   0);
            f32x4 a1 = __builtin_nontemporal_load(p + b +  64);
            f32x4 a2 = __builtin_nontemporal_load(p + b + 128);
            f32x4 a3 = __builtin_nontemporal_load(p + b + 192);
            float s = (a0.x + a0.y + a0.z + a0.w) + (a1.x + a1.y + a1.z + a1.w)
                    + (a2.x + a2.y + a2.z + a2.w) + (a3.x + a3.y + a3.z + a3.w);
            #pragma unroll
            for (int off = 32; off >= 1; off >>= 1) s += __shfl_xor(s, off);
            if (b == 0) st_sc1(&gT[pc * B_ + pb], s * (1.0f / (float)HW_));
        }
    }
    arrive_wait(ctr, GRID_);

    // ---- L1: h1T = gelu(bn1(g @ w1.T + b1)); 6 c per block ----
    {
        float* wl   = smem;          // [6][768]
        float* part = smem + 4608;   // [6][8][64]
        const int c0 = bid * 6;
        const float4* src = reinterpret_cast<const float4*>(w1 + (size_t)c0 * C_);
        float4* dst = reinterpret_cast<float4*>(wl);
        #pragma unroll
        for (int i = 0; i < 3; ++i) {
            int idx = t + i * THR_;
            if (idx < 1152) dst[idx] = src[idx];
        }
        __syncthreads();
        const int kc = w * 96;
        float acc[6] = {0.f, 0.f, 0.f, 0.f, 0.f, 0.f};
        const float* gp = gT + (size_t)kc * B_ + b;
        #pragma unroll 8
        for (int k = 0; k < 96; ++k) {
            float gv = gp[k * B_];
            #pragma unroll
            for (int j = 0; j < 6; ++j)
                acc[j] = fmaf(gv, wl[j * C_ + kc + k], acc[j]);
        }
        #pragma unroll
        for (int j = 0; j < 6; ++j) part[j * 512 + w * 64 + b] = acc[j];
        __syncthreads();
        if (t < 384) {
            const int ci = t >> 6, bb = t & 63, c = c0 + ci;
            float s = 0.f;
            #pragma unroll
            for (int ww = 0; ww < 8; ++ww) s += part[ci * 512 + ww * 64 + bb];
            s += b1[c];
            s = (s - bn1_m[c]) * rsqrtf(bn1_v[c] + 1e-5f) * bn1_g[c] + bn1_b[c];
            st_sc1(&h1T[(size_t)c * B_ + bb], gelu_exact(s));
        }
    }
    arrive_wait(ctr, 2 * GRID_);

    // ---- L2: rT = gelu(h1 @ caw1.T + cab1); 1 c per block, bid < 96 ----
    if (bid < R_) {
        float* wl   = smem;          // [1536]
        float* part = smem + C2_;    // [8][64]
        const float4* src = reinterpret_cast<const float4*>(caw1 + (size_t)bid * C2_);
        float4* dst = reinterpret_cast<float4*>(wl);
        if (t < 384) dst[t] = src[t];
        __syncthreads();
        const int kc = w * 192;
        float a0 = 0.f, a1 = 0.f;
        const float* hp = h1T + (size_t)kc * B_ + b;
        #pragma unroll 8
        for (int k = 0; k < 96; ++k) {
            a0 = fmaf(hp[k * B_],        wl[kc + k],      a0);
            a1 = fmaf(hp[(k + 96) * B_], wl[kc + k + 96], a1);
        }
        part[w * 64 + b] = a0 + a1;
        __syncthreads();
        if (t < 64) {
            float s = 0.f;
            #pragma unroll
            for (int ww = 0; ww < 8; ++ww) s += part[ww * 64 + t];
            st_sc1(&rT[(size_t)bid * B_ + t], gelu_exact(s + cab1[bid]));
        }
    }
    arrive_wait(ctr, 3 * GRID_);

    // ---- L3 gate: h1gT = h1T * sigmoid(2*(r @ caw2.T + cab2)); 6 c/block ---
    {
        const int c0 = bid * 6;
        if (w < 6) {
            const int c = c0 + w;
            const float* wr = caw2 + (size_t)c * R_;   // wave-uniform row
            const float* rp = rT + b;
            float a0 = 0.f, a1 = 0.f;
            #pragma unroll 8
            for (int k = 0; k < 48; ++k) {
                a0 = fmaf(rp[k * B_],        wr[k],      a0);
                a1 = fmaf(rp[(k + 48) * B_], wr[k + 48], a1);
            }
            float a = a0 + a1 + cab2[c];
            float sig = 1.0f / (1.0f + expf(-2.0f * a));
            float hv = h1T[(size_t)c * B_ + b];
            st_sc1(&h1gT[(size_t)c * B_ + b], hv * sig);
        }
    }
    arrive_wait(ctr, 4 * GRID_);

    // ---- L4: h2T = gelu(bn2(h1g @ w2.T + b2)); 3 c per block ----
    {
        float* wl   = smem;          // [3][1536]
        float* part = smem + 4608;   // [3][8][64]
        const int c0 = bid * 3;
        const float4* src = reinterpret_cast<const float4*>(w2 + (size_t)c0 * C2_);
        float4* dst = reinterpret_cast<float4*>(wl);
        #pragma unroll
        for (int i = 0; i < 3; ++i) {
            int idx = t + i * THR_;
            if (idx < 1152) dst[idx] = src[idx];
        }
        __syncthreads();
        const int kc = w * 192;
        float acc0[3] = {0.f, 0.f, 0.f};
        float acc1[3] = {0.f, 0.f, 0.f};
        const float* hp = h1gT + (size_t)kc * B_ + b;
        #pragma unroll 4
        for (int k = 0; k < 96; ++k) {
            float h0  = hp[k * B_];
            float h1v = hp[(k + 96) * B_];
            #pragma unroll
            for (int j = 0; j < 3; ++j) {
                acc0[j] = fmaf(h0,  wl[j * C2_ + kc + k],      acc0[j]);
                acc1[j] = fmaf(h1v, wl[j * C2_ + kc + k + 96], acc1[j]);
            }
        }
        #pragma unroll
        for (int j = 0; j < 3; ++j) part[j * 512 + w * 64 + b] = acc0[j] + acc1[j];
        __syncthreads();
        if (t < 192) {
            const int ci = t >> 6, bb = t & 63, c = c0 + ci;
            float s = 0.f;
            #pragma unroll
            for (int ww = 0; ww < 8; ++ww) s += part[ci * 512 + ww * 64 + bb];
            s += b2[c];
            s = (s - bn2_m[c]) * rsqrtf(bn2_v[c] + 1e-5f) * bn2_g[c] + bn2_b[c];
            st_sc1(&h2T[(size_t)c * B_ + bb], gelu_exact(s));
        }
    }
    arrive_wait(ctr, 5 * GRID_);

    // ---- L5: scores + top-2 + softmax; one block per b, bid < 64 ----
    if (bid < B_) {
        float* w3l  = smem;          // [16][769] padded (stride 769 -> no conflicts)
        float* h2l  = smem + 12304;  // [768]
        float* part = smem + 13072;  // [256]
        float* sc   = smem + 13328;  // [16]
        const int bb = bid;
        #pragma unroll
        for (int e = 0; e < E_; ++e)
            for (int i = t; i < C_; i += THR_)
                w3l[e * 769 + i] = w3[e * C_ + i];
        for (int k = t; k < C_; k += THR_) h2l[k] = h2T[(size_t)k * B_ + bb];
        __syncthreads();
        if (t < 256) {
            const int e = t & 15, kg = t >> 4;
            const float* wr = w3l + e * 769 + kg * 48;
            const float* hv = h2l + kg * 48;
            float acc = 0.f;
            #pragma unroll 8
            for (int j = 0; j < 48; ++j) acc = fmaf(hv[j], wr[j], acc);
            part[t] = acc;
        }
        __syncthreads();
        if (t < E_) {
            float s = b3[t];
            #pragma unroll
            for (int kg = 0; kg < 16; ++kg) s += part[kg * 16 + t];
            sc[t] = s;
        }
        __syncthreads();
        if (t == 0) {
            int i0 = 0; float v0 = sc[0];
            #pragma unroll
            for (int i = 1; i < E_; ++i) { if (sc[i] > v0) { v0 = sc[i]; i0 = i; } }
            int i1 = -1; float v1 = -INFINITY;
            #pragma unroll
            for (int i = 0; i < E_; ++i) {
                if (i == i0) continue;
                if (sc[i] > v1) { v1 = sc[i]; i1 = i; }
            }
            float e1 = expf((v1 - v0) * 0.5f);
            float inv = 1.0f / (1.0f + e1);
            out[bb * 2 + 0] = (float)i0;
            out[bb * 2 + 1] = (float)i1;
            out[2 * B_ + bb * 2 + 0] = inv;
            out[2 * B_ + bb * 2 + 1] = e1 * inv;
        }
    }
}

extern "C" void kernel_launch(void* const* d_in, const int* in_sizes, int n_in,
                              void* d_out, int out_size, void* d_ws, size_t ws_size,
                              hipStream_t stream) {
    const float* x     = (const float*)d_in[0];
    const float* w1    = (const float*)d_in[1];
    const float* b1    = (const float*)d_in[2];
    const float* bn1_g = (const float*)d_in[3];
    const float* bn1_b = (const float*)d_in[4];
    const float* bn1_m = (const float*)d_in[5];
    const float* bn1_v = (const float*)d_in[6];
    const float* caw1  = (const float*)d_in[7];
    const float* cab1  = (const float*)d_in[8];
    const float* caw2  = (const float*)d_in[9];
    const float* cab2  = (const float*)d_in[10];
    const float* w2    = (const float*)d_in[11];
    const float* b2    = (const float*)d_in[12];
    const float* bn2_g = (const float*)d_in[13];
    const float* bn2_b = (const float*)d_in[14];
    const float* bn2_m = (const float*)d_in[15];
    const float* bn2_v = (const float*)d_in[16];
    const float* w3    = (const float*)d_in[17];
    const float* b3    = (const float*)d_in[18];

    float* ws  = (float*)d_ws;
    float* gT   = ws;                  // [768][64]
    float* h1T  = ws + 49152;          // [1536][64]
    float* rT   = ws + 147456;         // [96][64]
    float* h2T  = ws + 153600;         // [768][64]
    float* h1gT = ws + 202752;         // [1536][64]
    unsigned* ctr = (unsigned*)(ws + 301056);
    float* out = (float*)d_out;

    hipMemsetAsync(ctr, 0, 4, stream);   // per-launch barrier reset (graph-safe)
    fused_all<<<GRID_, THR_, 0, stream>>>(
        x, w1, b1, bn1_g, bn1_b, bn1_m, bn1_v,
        caw1, cab1, caw2, cab2,
        w2, b2, bn2_g, bn2_b, bn2_m, bn2_v,
        w3, b3, gT, h1T, rT, h1gT, h2T, out, ctr);
}

// Round 8
// 80.955 us; speedup vs baseline: 1.2513x; 1.2513x over previous
//
#include <hip/hip_runtime.h>
#include <hip/hip_bf16.h>
#include <math.h>

#define B_   64
#define C_   768
#define C2_  1536
#define R_   96
#define E_   16
#define HW_  1024
#define GRID_ 512
#define THR_  512

typedef float f32x4 __attribute__((ext_vector_type(4)));

__device__ __forceinline__ float gelu_exact(float x) {
    return 0.5f * x * (1.0f + erff(x * 0.70710678118654752440f));
}

// relaxed agent-scope store: reaches coherence point, no L2 wb/inv emitted.
__device__ __forceinline__ void st_sc1(float* p, float v) {
    __hip_atomic_store(p, v, __ATOMIC_RELAXED, __HIP_MEMORY_SCOPE_AGENT);
}

// Grid barrier v3: distinct-flag arrival stores (no same-line RMW
// serialization), block-0 aggregates via load-only poll, publishes go word.
__device__ __forceinline__ void gbar(unsigned* flags, unsigned* go, int idx) {
    const int t = threadIdx.x, bid = blockIdx.x;
    __syncthreads();
    if (t == 0) {
        asm volatile("s_waitcnt vmcnt(0)" ::: "memory");
        __hip_atomic_store(&flags[idx * GRID_ + bid], 1u,
                           __ATOMIC_RELAXED, __HIP_MEMORY_SCOPE_AGENT);
    }
    if (bid == 0) {
        if (t < 64) {
            const unsigned* f = flags + idx * GRID_ + t * (GRID_ / 64);
            int it = 0;
            for (;;) {
                unsigned all1 = 1;
                #pragma unroll
                for (int j = 0; j < GRID_ / 64; ++j)
                    all1 &= __hip_atomic_load(&f[j], __ATOMIC_RELAXED,
                                              __HIP_MEMORY_SCOPE_AGENT);
                if (__all(all1 == 1u)) break;
                __builtin_amdgcn_s_sleep(4);
                if (++it > (1 << 20)) break;   // safety valve
            }
        }
        __syncthreads();
        if (t == 0)
            __hip_atomic_store(&go[idx], 1u, __ATOMIC_RELAXED,
                               __HIP_MEMORY_SCOPE_AGENT);
    } else if (t == 0) {
        int it = 0;
        while (__hip_atomic_load(&go[idx], __ATOMIC_RELAXED,
                                 __HIP_MEMORY_SCOPE_AGENT) != 1u) {
            __builtin_amdgcn_s_sleep(4);
            if (++it > (1 << 20)) break;       // safety valve
        }
    }
    __syncthreads();
}

// -------- Kernel 1: global average pool [B,C,H,W] -> gT[C][B] ---------------
// one wave per row; 12288 blocks -> full occupancy, HBM-bound (~88% peak).
__global__ __launch_bounds__(256) void pool_kernel(const float* __restrict__ x,
                                                   float* __restrict__ gT) {
    const int wave = threadIdx.x >> 6;
    const int lane = threadIdx.x & 63;
    const int row  = blockIdx.x * 4 + wave;
    const int b = row / C_;
    const int c = row % C_;
    const f32x4* p = reinterpret_cast<const f32x4*>(x + (size_t)row * HW_);
    f32x4 a0 = __builtin_nontemporal_load(p + lane +   0);
    f32x4 a1 = __builtin_nontemporal_load(p + lane +  64);
    f32x4 a2 = __builtin_nontemporal_load(p + lane + 128);
    f32x4 a3 = __builtin_nontemporal_load(p + lane + 192);
    float s = (a0.x + a0.y + a0.z + a0.w) + (a1.x + a1.y + a1.z + a1.w)
            + (a2.x + a2.y + a2.z + a2.w) + (a3.x + a3.y + a3.z + a3.w);
    #pragma unroll
    for (int off = 32; off >= 1; off >>= 1) s += __shfl_xor(s, off);
    if (lane == 0) gT[c * B_ + b] = s * (1.0f / (float)HW_);
}

// -------- Kernel 2: gating chain, 512 blocks (2/CU), flag-array barriers ----
__global__ __launch_bounds__(512) void fused_chain(
    const float* __restrict__ gT,
    const float* __restrict__ w1, const float* __restrict__ b1,
    const float* __restrict__ bn1_g, const float* __restrict__ bn1_b,
    const float* __restrict__ bn1_m, const float* __restrict__ bn1_v,
    const float* __restrict__ caw1, const float* __restrict__ cab1,
    const float* __restrict__ caw2, const float* __restrict__ cab2,
    const float* __restrict__ w2, const float* __restrict__ b2,
    const float* __restrict__ bn2_g, const float* __restrict__ bn2_b,
    const float* __restrict__ bn2_m, const float* __restrict__ bn2_v,
    const float* __restrict__ w3, const float* __restrict__ b3,
    float* __restrict__ h1T, float* __restrict__ rT,
    float* __restrict__ h1gT, float* __restrict__ h2T,
    float* __restrict__ out, unsigned* __restrict__ flags,
    unsigned* __restrict__ go)
{
    __shared__ float smem[13456];   // 53.8 KB -> 2 blocks/CU
    const int t   = threadIdx.x;
    const int bid = blockIdx.x;
    const int b   = t & 63;
    const int w   = t >> 6;

    // ---- L1: h1T = gelu(bn1(g @ w1.T + b1)); 3 c per block ----
    {
        float* wl   = smem;          // [3][768]
        float* part = smem + 2304;   // [3][8][64]
        const int c0 = bid * 3;
        const float4* src = reinterpret_cast<const float4*>(w1 + (size_t)c0 * C_);
        float4* dst = reinterpret_cast<float4*>(wl);
        #pragma unroll
        for (int i = 0; i < 2; ++i) {
            int idx = t + i * THR_;
            if (idx < 576) dst[idx] = src[idx];
        }
        __syncthreads();
        const int kc = w * 96;
        float acc[3] = {0.f, 0.f, 0.f};
        const float* gp = gT + (size_t)kc * B_ + b;
        #pragma unroll 8
        for (int k = 0; k < 96; ++k) {
            float gv = gp[k * B_];
            #pragma unroll
            for (int j = 0; j < 3; ++j)
                acc[j] = fmaf(gv, wl[j * C_ + kc + k], acc[j]);
        }
        #pragma unroll
        for (int j = 0; j < 3; ++j) part[j * 512 + w * 64 + b] = acc[j];
        __syncthreads();
        if (t < 192) {
            const int ci = t >> 6, bb = t & 63, c = c0 + ci;
            float s = 0.f;
            #pragma unroll
            for (int ww = 0; ww < 8; ++ww) s += part[ci * 512 + ww * 64 + bb];
            s += b1[c];
            s = (s - bn1_m[c]) * rsqrtf(bn1_v[c] + 1e-5f) * bn1_g[c] + bn1_b[c];
            st_sc1(&h1T[(size_t)c * B_ + bb], gelu_exact(s));
        }
    }
    gbar(flags, go, 0);

    // ---- L2: rT = gelu(h1 @ caw1.T + cab1); 1 c per block, bid < 96 ----
    if (bid < R_) {
        float* wl   = smem;          // [1536]
        float* part = smem + C2_;    // [8][64]
        const float4* src = reinterpret_cast<const float4*>(caw1 + (size_t)bid * C2_);
        float4* dst = reinterpret_cast<float4*>(wl);
        if (t < 384) dst[t] = src[t];
        __syncthreads();
        const int kc = w * 192;
        float a0 = 0.f, a1 = 0.f;
        const float* hp = h1T + (size_t)kc * B_ + b;
        #pragma unroll 8
        for (int k = 0; k < 96; ++k) {
            a0 = fmaf(hp[k * B_],        wl[kc + k],      a0);
            a1 = fmaf(hp[(k + 96) * B_], wl[kc + k + 96], a1);
        }
        part[w * 64 + b] = a0 + a1;
        __syncthreads();
        if (t < 64) {
            float s = 0.f;
            #pragma unroll
            for (int ww = 0; ww < 8; ++ww) s += part[ww * 64 + t];
            st_sc1(&rT[(size_t)bid * B_ + t], gelu_exact(s + cab1[bid]));
        }
    }
    gbar(flags, go, 1);

    // ---- L3 gate: h1gT = h1T * sigmoid(2*(r @ caw2.T + cab2)); 3 c/block ---
    {
        const int c0 = bid * 3;
        if (w < 3) {
            const int c = c0 + w;
            const float* wr = caw2 + (size_t)c * R_;   // wave-uniform row
            const float* rp = rT + b;
            float a0 = 0.f, a1 = 0.f;
            #pragma unroll 8
            for (int k = 0; k < 48; ++k) {
                a0 = fmaf(rp[k * B_],        wr[k],      a0);
                a1 = fmaf(rp[(k + 48) * B_], wr[k + 48], a1);
            }
            float a = a0 + a1 + cab2[c];
            float sig = 1.0f / (1.0f + expf(-2.0f * a));
            float hv = h1T[(size_t)c * B_ + b];
            st_sc1(&h1gT[(size_t)c * B_ + b], hv * sig);
        }
    }
    gbar(flags, go, 2);

    // ---- L4: h2T = gelu(bn2(h1g @ w2.T + b2)); 2 c per block, bid < 384 ----
    if (bid < 384) {
        float* wl   = smem;          // [2][1536]
        float* part = smem + 3072;   // [2][8][64]
        const int c0 = bid * 2;
        const float4* src = reinterpret_cast<const float4*>(w2 + (size_t)c0 * C2_);
        float4* dst = reinterpret_cast<float4*>(wl);
        #pragma unroll
        for (int i = 0; i < 2; ++i) {
            int idx = t + i * THR_;
            if (idx < 768) dst[idx] = src[idx];
        }
        __syncthreads();
        const int kc = w * 192;
        float acc0[2] = {0.f, 0.f};
        float acc1[2] = {0.f, 0.f};
        const float* hp = h1gT + (size_t)kc * B_ + b;
        #pragma unroll 4
        for (int k = 0; k < 96; ++k) {
            float h0  = hp[k * B_];
            float h1v = hp[(k + 96) * B_];
            #pragma unroll
            for (int j = 0; j < 2; ++j) {
                acc0[j] = fmaf(h0,  wl[j * C2_ + kc + k],      acc0[j]);
                acc1[j] = fmaf(h1v, wl[j * C2_ + kc + k + 96], acc1[j]);
            }
        }
        #pragma unroll
        for (int j = 0; j < 2; ++j) part[j * 512 + w * 64 + b] = acc0[j] + acc1[j];
        __syncthreads();
        if (t < 128) {
            const int ci = t >> 6, bb = t & 63, c = c0 + ci;
            float s = 0.f;
            #pragma unroll
            for (int ww = 0; ww < 8; ++ww) s += part[ci * 512 + ww * 64 + bb];
            s += b2[c];
            s = (s - bn2_m[c]) * rsqrtf(bn2_v[c] + 1e-5f) * bn2_g[c] + bn2_b[c];
            st_sc1(&h2T[(size_t)c * B_ + bb], gelu_exact(s));
        }
    }
    gbar(flags, go, 3);

    // ---- L5: scores + top-2 + softmax; one block per b, bid < 64 ----
    if (bid < B_) {
        float* w3l  = smem;          // [16][769] padded (stride 769 -> no conflicts)
        float* h2l  = smem + 12304;  // [768]
        float* part = smem + 13072;  // [256]
        float* sc   = smem + 13328;  // [16]
        const int bb = bid;
        #pragma unroll
        for (int e = 0; e < E_; ++e)
            for (int i = t; i < C_; i += THR_)
                w3l[e * 769 + i] = w3[e * C_ + i];
        for (int k = t; k < C_; k += THR_) h2l[k] = h2T[(size_t)k * B_ + bb];
        __syncthreads();
        if (t < 256) {
            const int e = t & 15, kg = t >> 4;
            const float* wr = w3l + e * 769 + kg * 48;
            const float* hv = h2l + kg * 48;
            float acc = 0.f;
            #pragma unroll 8
            for (int j = 0; j < 48; ++j) acc = fmaf(hv[j], wr[j], acc);
            part[t] = acc;
        }
        __syncthreads();
        if (t < E_) {
            float s = b3[t];
            #pragma unroll
            for (int kg = 0; kg < 16; ++kg) s += part[kg * 16 + t];
            sc[t] = s;
        }
        __syncthreads();
        if (t == 0) {
            int i0 = 0; float v0 = sc[0];
            #pragma unroll
            for (int i = 1; i < E_; ++i) { if (sc[i] > v0) { v0 = sc[i]; i0 = i; } }
            int i1 = -1; float v1 = -INFINITY;
            #pragma unroll
            for (int i = 0; i < E_; ++i) {
                if (i == i0) continue;
                if (sc[i] > v1) { v1 = sc[i]; i1 = i; }
            }
            float e1 = expf((v1 - v0) * 0.5f);
            float inv = 1.0f / (1.0f + e1);
            out[bb * 2 + 0] = (float)i0;
            out[bb * 2 + 1] = (float)i1;
            out[2 * B_ + bb * 2 + 0] = inv;
            out[2 * B_ + bb * 2 + 1] = e1 * inv;
        }
    }
}

extern "C" void kernel_launch(void* const* d_in, const int* in_sizes, int n_in,
                              void* d_out, int out_size, void* d_ws, size_t ws_size,
                              hipStream_t stream) {
    const float* x     = (const float*)d_in[0];
    const float* w1    = (const float*)d_in[1];
    const float* b1    = (const float*)d_in[2];
    const float* bn1_g = (const float*)d_in[3];
    const float* bn1_b = (const float*)d_in[4];
    const float* bn1_m = (const float*)d_in[5];
    const float* bn1_v = (const float*)d_in[6];
    const float* caw1  = (const float*)d_in[7];
    const float* cab1  = (const float*)d_in[8];
    const float* caw2  = (const float*)d_in[9];
    const float* cab2  = (const float*)d_in[10];
    const float* w2    = (const float*)d_in[11];
    const float* b2    = (const float*)d_in[12];
    const float* bn2_g = (const float*)d_in[13];
    const float* bn2_b = (const float*)d_in[14];
    const float* bn2_m = (const float*)d_in[15];
    const float* bn2_v = (const float*)d_in[16];
    const float* w3    = (const float*)d_in[17];
    const float* b3    = (const float*)d_in[18];

    float* ws   = (float*)d_ws;
    float* gT   = ws;                  // [768][64]
    float* h1T  = ws + 49152;          // [1536][64]
    float* rT   = ws + 147456;         // [96][64]
    float* h2T  = ws + 153600;         // [768][64]
    float* h1gT = ws + 202752;         // [1536][64]
    unsigned* flags = (unsigned*)(ws + 301056);   // [4][512]
    unsigned* go    = flags + 4 * GRID_;          // [4]
    float* out = (float*)d_out;

    hipMemsetAsync(flags, 0, (4 * GRID_ + 4) * sizeof(unsigned), stream);
    pool_kernel<<<(B_ * C_) / 4, 256, 0, stream>>>(x, gT);
    fused_chain<<<GRID_, THR_, 0, stream>>>(
        gT, w1, b1, bn1_g, bn1_b, bn1_m, bn1_v,
        caw1, cab1, caw2, cab2,
        w2, b2, bn2_g, bn2_b, bn2_m, bn2_v,
        w3, b3, h1T, rT, h1gT, h2T, out, flags, go);
}